// Round 1
// baseline (1370.852 us; speedup 1.0000x reference)
//
#include <hip/hip_runtime.h>

#pragma clang fp contract(off)

#define BATCH 16
#define NPTS  4096
#define KNN   32
#define QPB   256   // queries (threads) per block
#define CH    30

// Order-preserving float->uint encoding for atomic max (handles negatives).
__device__ __forceinline__ unsigned enc_f32(float f) {
    unsigned u = __float_as_uint(f);
    return (u & 0x80000000u) ? ~u : (u | 0x80000000u);
}
__device__ __forceinline__ float dec_f32(unsigned e) {
    unsigned u = (e & 0x80000000u) ? (e & 0x7FFFFFFFu) : ~e;
    return __uint_as_float(u);
}

__global__ void init_pool_kernel(unsigned* __restrict__ pool) {
    int i = blockIdx.x * blockDim.x + threadIdx.x;
    if (i < BATCH * CH) pool[i] = 0u;   // 0 is below every encoded finite float
}

__launch_bounds__(QPB)
__global__ void knn_feat_kernel(const float* __restrict__ x,
                                unsigned* __restrict__ pool) {
    __shared__ float4 pts[NPTS];                 // {x, y, z, |p|^2}  = 64 KB
    const int b     = blockIdx.x >> 4;           // NPTS/QPB == 16 chunks/batch
    const int chunk = blockIdx.x & 15;
    const int tid   = threadIdx.x;
    const float* __restrict__ xb = x + (size_t)b * NPTS * 3;

    // Stage the whole batch into LDS (SoA-in-float4), precompute |p|^2.
    for (int i = tid; i < NPTS; i += QPB) {
        float px = xb[i * 3 + 0];
        float py = xb[i * 3 + 1];
        float pz = xb[i * 3 + 2];
        float sq = px * px + py * py + pz * pz;
        pts[i] = make_float4(px, py, pz, sq);
    }
    __syncthreads();

    const int n = chunk * QPB + tid;             // this thread's query point
    const float4 q = pts[n];

    // ---- Pass 1: maintain the 32 smallest distance VALUES (sorted asc). ----
    float arr[KNN];
#pragma unroll
    for (int j = 0; j < KNN; ++j) arr[j] = __builtin_inff();

    for (int m = 0; m < NPTS; ++m) {
        float4 p = pts[m];                        // LDS broadcast (uniform addr)
        float dot = q.x * p.x + q.y * p.y + q.z * p.z;
        float d   = q.w + p.w - 2.0f * dot;       // matches sq_n + sq_m - 2*dot
        if (d < arr[KNN - 1]) {
            float t = d;                          // min/max bubble insert (64 ops)
#pragma unroll
            for (int j = 0; j < KNN; ++j) {
                float lo = fminf(arr[j], t);
                float hi = fmaxf(arr[j], t);
                arr[j] = lo;
                t = hi;                           // largest gets ejected
            }
        }
    }

    const float thr = arr[KNN - 1];               // 32nd smallest distance
    int c_lt = 0;
#pragma unroll
    for (int j = 0; j < KNN; ++j) c_lt += (arr[j] < thr) ? 1 : 0;
    int need_eq = KNN - c_lt;                     // ties taken in index order

    // ---- Pass 2: accumulate neighbor statistics. ----
    float s0 = 0.f, s1 = 0.f, s2 = 0.f;           // sum(rel)
    float ss0 = 0.f, ss1 = 0.f, ss2 = 0.f;        // sum(rel^2)
    float mx0 = -__builtin_inff(), mx1 = -__builtin_inff(), mx2 = -__builtin_inff();
    float mn0 =  __builtin_inff(), mn1 =  __builtin_inff(), mn2 =  __builtin_inff();

    for (int m = 0; m < NPTS; ++m) {
        float4 p = pts[m];
        float dot = q.x * p.x + q.y * p.y + q.z * p.z;
        float d   = q.w + p.w - 2.0f * dot;       // bit-identical to pass 1
        bool take = false;
        if (d < thr) {
            take = true;
        } else if (d == thr && need_eq > 0) {
            take = true;
            need_eq -= 1;
        }
        if (take) {
            float r0 = p.x - q.x, r1 = p.y - q.y, r2 = p.z - q.z;
            s0 += r0;  s1 += r1;  s2 += r2;
            ss0 += r0 * r0;  ss1 += r1 * r1;  ss2 += r2 * r2;
            mx0 = fmaxf(mx0, r0); mx1 = fmaxf(mx1, r1); mx2 = fmaxf(mx2, r2);
            mn0 = fminf(mn0, r0); mn1 = fminf(mn1, r1); mn2 = fminf(mn2, r2);
        }
    }

    // ---- 30 channels ----
    const float invk = 1.0f / (float)KNN;
    float mu0 = s0 * invk, mu1 = s1 * invk, mu2 = s2 * invk;
    float ex0 = ss0 * invk, ex1 = ss1 * invk, ex2 = ss2 * invk;   // mean(rel^2)
    float st0 = sqrtf(fmaxf(ex0 - mu0 * mu0, 0.f));
    float st1 = sqrtf(fmaxf(ex1 - mu1 * mu1, 0.f));
    float st2 = sqrtf(fmaxf(ex2 - mu2 * mu2, 0.f));
    float nrm = sqrtf(mu0 * mu0 + mu1 * mu1 + mu2 * mu2) + 1e-8f;
    float u0 = mu0 / nrm, u1 = mu1 / nrm, u2 = mu2 / nrm;
    float cr0 = q.y * u2 - q.z * u1;              // cross(x, unit_mu)
    float cr1 = q.z * u0 - q.x * u2;
    float cr2 = q.x * u1 - q.y * u0;
    float mq0 = fmaxf(mx0 * mx0, mn0 * mn0);      // max(rel^2)
    float mq1 = fmaxf(mx1 * mx1, mn1 * mn1);
    float mq2 = fmaxf(mx2 * mx2, mn2 * mn2);

    float f[CH] = { q.x, q.y, q.z,
                    mu0, mu1, mu2,
                    mx0, mx1, mx2,
                    mn0, mn1, mn2,
                    st0, st1, st2,
                    q.x - mu0, q.y - mu1, q.z - mu2,
                    u0, u1, u2,
                    cr0, cr1, cr2,
                    mq0, mq1, mq2,
                    ex0, ex1, ex2 };

    // ---- Wave max-reduce per channel, then one atomic per wave. ----
#pragma unroll
    for (int c = 0; c < CH; ++c) {
        float v = f[c];
#pragma unroll
        for (int off = 32; off >= 1; off >>= 1)
            v = fmaxf(v, __shfl_xor(v, off, 64));
        if ((tid & 63) == 0)
            atomicMax(pool + b * CH + c, enc_f32(v));
    }
}

__global__ void final_mm_kernel(const unsigned* __restrict__ pool,
                                const float* __restrict__ W,
                                const float* __restrict__ bias,
                                float* __restrict__ out) {
    int t = blockIdx.x * blockDim.x + threadIdx.x;
    if (t >= BATCH * 32) return;
    int bb = t >> 5, e = t & 31;
    float acc = bias[e];
#pragma unroll
    for (int c = 0; c < CH; ++c)
        acc += dec_f32(pool[bb * CH + c]) * W[e * CH + c];
    out[bb * 32 + e] = acc;
}

extern "C" void kernel_launch(void* const* d_in, const int* in_sizes, int n_in,
                              void* d_out, int out_size, void* d_ws, size_t ws_size,
                              hipStream_t stream) {
    const float* x    = (const float*)d_in[0];   // [16, 4096, 3] f32
    const float* W    = (const float*)d_in[1];   // [32, 30] f32
    const float* bias = (const float*)d_in[2];   // [32] f32
    float*       out  = (float*)d_out;           // [16, 32] f32
    unsigned*    pool = (unsigned*)d_ws;         // [16, 30] encoded f32

    hipLaunchKernelGGL(init_pool_kernel, dim3(1), dim3(512), 0, stream, pool);
    hipLaunchKernelGGL(knn_feat_kernel, dim3(BATCH * (NPTS / QPB)), dim3(QPB), 0, stream,
                       x, pool);
    hipLaunchKernelGGL(final_mm_kernel, dim3(1), dim3(512), 0, stream, pool, W, bias, out);
}

// Round 2
// 1088.823 us; speedup vs baseline: 1.2590x; 1.2590x over previous
//
#include <hip/hip_runtime.h>

#pragma clang fp contract(off)

#define BATCH 16
#define NPTS  4096
#define KNN   32
#define NW    4                 // waves per block = candidate-chunk split factor
#define CHUNK (NPTS / NW)       // 1024 candidates per wave
#define CH    30

#define INF_F __builtin_inff()

// Order-preserving float->uint encoding for atomic max (handles negatives).
__device__ __forceinline__ unsigned enc_f32(float f) {
    unsigned u = __float_as_uint(f);
    return (u & 0x80000000u) ? ~u : (u | 0x80000000u);
}
__device__ __forceinline__ float dec_f32(unsigned e) {
    unsigned u = (e & 0x80000000u) ? (e & 0x7FFFFFFFu) : ~e;
    return __uint_as_float(u);
}

__global__ void init_pool_kernel(unsigned* __restrict__ pool) {
    int i = blockIdx.x * blockDim.x + threadIdx.x;
    if (i < BATCH * CH) pool[i] = 0u;   // 0 is below every encoded finite float
}

// Block: 256 threads = 4 waves. Lane l owns query (qg*64 + l); wave w scans
// candidate chunk [w*1024, w*1024+1024). Partial top-32 lists merged in LDS.
__launch_bounds__(256, 4)
__global__ void knn_feat_kernel(const float* __restrict__ x,
                                unsigned* __restrict__ pool) {
    __shared__ float buf[NW * KNN * 64];         // [w][j][l] lane-contiguous, 32 KB
    const int b   = blockIdx.x >> 6;             // 64 query-groups per batch
    const int qg  = blockIdx.x & 63;
    const int tid = threadIdx.x;
    const int w   = tid >> 6;                    // wave id = chunk id
    const int l   = tid & 63;                    // lane = query slot
    const int q   = qg * 64 + l;
    const float* __restrict__ xb = x + (size_t)b * NPTS * 3;

    const float qx = xb[q * 3 + 0];
    const float qy = xb[q * 3 + 1];
    const float qz = xb[q * 3 + 2];
    const float qw = qx * qx + qy * qy + qz * qz;

    // ---- Pass 1: top-32 distance VALUES of my chunk (sorted asc). ----
    float arr[KNN];
#pragma unroll
    for (int j = 0; j < KNN; ++j) arr[j] = INF_F;

    {
        const float* __restrict__ cp = xb + (size_t)(w * CHUNK) * 3;
        for (int m = 0; m < CHUNK; ++m) {
            float px = cp[0], py = cp[1], pz = cp[2];
            cp += 3;
            float pw  = px * px + py * py + pz * pz;   // bit-identical both passes
            float dot = qx * px + qy * py + qz * pz;
            float d   = qw + pw - 2.0f * dot;
            // Mask-free bubble: a value >= arr[31] falls straight through and
            // leaves arr unchanged, so no per-lane predication is needed.
            if (__any(d < arr[KNN - 1])) {
                float t = d;
#pragma unroll
                for (int j = 0; j < KNN; ++j) {
                    float lo = fminf(arr[j], t);
                    float hi = fmaxf(arr[j], t);
                    arr[j] = lo;
                    t = hi;
                }
            }
        }
    }

#pragma unroll
    for (int j = 0; j < KNN; ++j) buf[(w * KNN + j) * 64 + l] = arr[j];
    __syncthreads();

    // ---- Merge the 4 sorted lists for query l (done redundantly per wave):
    // thr = 32nd smallest of the union == global 32nd smallest distance.
    float thr;
    {
        float v0 = buf[(0 * KNN) * 64 + l];
        float v1 = buf[(1 * KNN) * 64 + l];
        float v2 = buf[(2 * KNN) * 64 + l];
        float v3 = buf[(3 * KNN) * 64 + l];
        int h0 = 1, h1 = 1, h2 = 1, h3 = 1;
        float mv = 0.f;
#pragma unroll 1
        for (int it = 0; it < KNN; ++it) {
            mv = fminf(fminf(v0, v1), fminf(v2, v3));
            if (it == KNN - 1) break;
            if (v0 == mv)      { v0 = (h0 < KNN) ? buf[(0 * KNN + h0) * 64 + l] : INF_F; ++h0; }
            else if (v1 == mv) { v1 = (h1 < KNN) ? buf[(1 * KNN + h1) * 64 + l] : INF_F; ++h1; }
            else if (v2 == mv) { v2 = (h2 < KNN) ? buf[(2 * KNN + h2) * 64 + l] : INF_F; ++h2; }
            else               { v3 = (h3 < KNN) ? buf[(3 * KNN + h3) * 64 + l] : INF_F; ++h3; }
        }
        thr = mv;
    }

    // Counts per chunk: everything < thr is provably inside its chunk's top-32.
    int lt0 = 0, lt1 = 0, lt2 = 0, lt3 = 0;
    int eq0 = 0, eq1 = 0, eq2 = 0, eq3 = 0;
#pragma unroll
    for (int j = 0; j < KNN; ++j) {
        float a0 = buf[(0 * KNN + j) * 64 + l]; lt0 += a0 < thr; eq0 += a0 == thr;
        float a1 = buf[(1 * KNN + j) * 64 + l]; lt1 += a1 < thr; eq1 += a1 == thr;
        float a2 = buf[(2 * KNN + j) * 64 + l]; lt2 += a2 < thr; eq2 += a2 == thr;
        float a3 = buf[(3 * KNN + j) * 64 + l]; lt3 += a3 < thr; eq3 += a3 == thr;
    }
    const int need = KNN - (lt0 + lt1 + lt2 + lt3);   // ties to take globally
    int before, quota;
    if (w == 0)      before = 0;
    else if (w == 1) before = eq0;
    else if (w == 2) before = eq0 + eq1;
    else             before = eq0 + eq1 + eq2;
    quota = need - before;
    if (quota < 0) quota = 0;                          // ties taken in index order

    __syncthreads();   // all list reads done; buf will be reused for stats

    // ---- Pass 2: accumulate neighbor statistics over my chunk. ----
    float s0 = 0.f, s1 = 0.f, s2 = 0.f;
    float ss0 = 0.f, ss1 = 0.f, ss2 = 0.f;
    float mx0 = -INF_F, mx1 = -INF_F, mx2 = -INF_F;
    float mn0 =  INF_F, mn1 =  INF_F, mn2 =  INF_F;
    int taken_eq = 0;
    {
        const float* __restrict__ cp = xb + (size_t)(w * CHUNK) * 3;
        for (int m = 0; m < CHUNK; ++m) {
            float px = cp[0], py = cp[1], pz = cp[2];
            cp += 3;
            float pw  = px * px + py * py + pz * pz;
            float dot = qx * px + qy * py + qz * pz;
            float d   = qw + pw - 2.0f * dot;          // bit-identical to pass 1
            bool take = d < thr;
            if (!take && d == thr && taken_eq < quota) { take = true; ++taken_eq; }
            if (take) {
                float r0 = px - qx, r1 = py - qy, r2 = pz - qz;
                s0 += r0;  s1 += r1;  s2 += r2;
                ss0 += r0 * r0;  ss1 += r1 * r1;  ss2 += r2 * r2;
                mx0 = fmaxf(mx0, r0); mx1 = fmaxf(mx1, r1); mx2 = fmaxf(mx2, r2);
                mn0 = fminf(mn0, r0); mn1 = fminf(mn1, r1); mn2 = fminf(mn2, r2);
            }
        }
    }

    // Stash partial stats [w][c][l] (12 channels), reusing buf.
    buf[(w * 12 +  0) * 64 + l] = s0;   buf[(w * 12 +  1) * 64 + l] = s1;
    buf[(w * 12 +  2) * 64 + l] = s2;   buf[(w * 12 +  3) * 64 + l] = ss0;
    buf[(w * 12 +  4) * 64 + l] = ss1;  buf[(w * 12 +  5) * 64 + l] = ss2;
    buf[(w * 12 +  6) * 64 + l] = mx0;  buf[(w * 12 +  7) * 64 + l] = mx1;
    buf[(w * 12 +  8) * 64 + l] = mx2;  buf[(w * 12 +  9) * 64 + l] = mn0;
    buf[(w * 12 + 10) * 64 + l] = mn1;  buf[(w * 12 + 11) * 64 + l] = mn2;
    __syncthreads();

    if (w != 0) return;   // no barriers past this point

    // ---- Combine 4 partials, build 30 channels, block-max, one atomic set. ----
#define RD(ww, c) buf[((ww) * 12 + (c)) * 64 + l]
    s0  = RD(0,0) + RD(1,0) + RD(2,0) + RD(3,0);
    s1  = RD(0,1) + RD(1,1) + RD(2,1) + RD(3,1);
    s2  = RD(0,2) + RD(1,2) + RD(2,2) + RD(3,2);
    ss0 = RD(0,3) + RD(1,3) + RD(2,3) + RD(3,3);
    ss1 = RD(0,4) + RD(1,4) + RD(2,4) + RD(3,4);
    ss2 = RD(0,5) + RD(1,5) + RD(2,5) + RD(3,5);
    mx0 = fmaxf(fmaxf(RD(0,6), RD(1,6)), fmaxf(RD(2,6), RD(3,6)));
    mx1 = fmaxf(fmaxf(RD(0,7), RD(1,7)), fmaxf(RD(2,7), RD(3,7)));
    mx2 = fmaxf(fmaxf(RD(0,8), RD(1,8)), fmaxf(RD(2,8), RD(3,8)));
    mn0 = fminf(fminf(RD(0,9), RD(1,9)), fminf(RD(2,9), RD(3,9)));
    mn1 = fminf(fminf(RD(0,10), RD(1,10)), fminf(RD(2,10), RD(3,10)));
    mn2 = fminf(fminf(RD(0,11), RD(1,11)), fminf(RD(2,11), RD(3,11)));
#undef RD

    const float invk = 1.0f / (float)KNN;
    float mu0 = s0 * invk, mu1 = s1 * invk, mu2 = s2 * invk;
    float ex0 = ss0 * invk, ex1 = ss1 * invk, ex2 = ss2 * invk;
    float st0 = sqrtf(fmaxf(ex0 - mu0 * mu0, 0.f));
    float st1 = sqrtf(fmaxf(ex1 - mu1 * mu1, 0.f));
    float st2 = sqrtf(fmaxf(ex2 - mu2 * mu2, 0.f));
    float nrm = sqrtf(mu0 * mu0 + mu1 * mu1 + mu2 * mu2) + 1e-8f;
    float u0 = mu0 / nrm, u1 = mu1 / nrm, u2 = mu2 / nrm;
    float cr0 = qy * u2 - qz * u1;
    float cr1 = qz * u0 - qx * u2;
    float cr2 = qx * u1 - qy * u0;
    float mq0 = fmaxf(mx0 * mx0, mn0 * mn0);
    float mq1 = fmaxf(mx1 * mx1, mn1 * mn1);
    float mq2 = fmaxf(mx2 * mx2, mn2 * mn2);

    float f[CH] = { qx, qy, qz,
                    mu0, mu1, mu2,
                    mx0, mx1, mx2,
                    mn0, mn1, mn2,
                    st0, st1, st2,
                    qx - mu0, qy - mu1, qz - mu2,
                    u0, u1, u2,
                    cr0, cr1, cr2,
                    mq0, mq1, mq2,
                    ex0, ex1, ex2 };

#pragma unroll
    for (int c = 0; c < CH; ++c) {
        float v = f[c];
#pragma unroll
        for (int off = 32; off >= 1; off >>= 1)
            v = fmaxf(v, __shfl_xor(v, off, 64));
        if (l == 0)
            atomicMax(pool + b * CH + c, enc_f32(v));
    }
}

__global__ void final_mm_kernel(const unsigned* __restrict__ pool,
                                const float* __restrict__ W,
                                const float* __restrict__ bias,
                                float* __restrict__ out) {
    int t = blockIdx.x * blockDim.x + threadIdx.x;
    if (t >= BATCH * 32) return;
    int bb = t >> 5, e = t & 31;
    float acc = bias[e];
#pragma unroll
    for (int c = 0; c < CH; ++c)
        acc += dec_f32(pool[bb * CH + c]) * W[e * CH + c];
    out[bb * 32 + e] = acc;
}

extern "C" void kernel_launch(void* const* d_in, const int* in_sizes, int n_in,
                              void* d_out, int out_size, void* d_ws, size_t ws_size,
                              hipStream_t stream) {
    const float* x    = (const float*)d_in[0];   // [16, 4096, 3] f32
    const float* W    = (const float*)d_in[1];   // [32, 30] f32
    const float* bias = (const float*)d_in[2];   // [32] f32
    float*       out  = (float*)d_out;           // [16, 32] f32
    unsigned*    pool = (unsigned*)d_ws;         // [16, 30] encoded f32

    hipLaunchKernelGGL(init_pool_kernel, dim3(1), dim3(512), 0, stream, pool);
    hipLaunchKernelGGL(knn_feat_kernel, dim3(BATCH * (NPTS / 64)), dim3(256), 0, stream,
                       x, pool);
    hipLaunchKernelGGL(final_mm_kernel, dim3(1), dim3(512), 0, stream, pool, W, bias, out);
}

// Round 3
// 612.126 us; speedup vs baseline: 2.2395x; 1.7788x over previous
//
#include <hip/hip_runtime.h>

#pragma clang fp contract(off)

#define BATCH 16
#define NPTS  4096
#define KNN   32
#define NW    4                 // waves per block = candidate-chunk split factor
#define CHUNK (NPTS / NW)       // 1024 candidates per wave
#define CH    30

#define INF_F __builtin_inff()

// Order-preserving float->uint encoding for atomic max (handles negatives).
__device__ __forceinline__ unsigned enc_f32(float f) {
    unsigned u = __float_as_uint(f);
    return (u & 0x80000000u) ? ~u : (u | 0x80000000u);
}
__device__ __forceinline__ float dec_f32(unsigned e) {
    unsigned u = (e & 0x80000000u) ? (e & 0x7FFFFFFFu) : ~e;
    return __uint_as_float(u);
}

__device__ __forceinline__ float med3f(float a, float b, float c) {
#if __has_builtin(__builtin_amdgcn_fmed3f)
    return __builtin_amdgcn_fmed3f(a, b, c);
#else
    float r;
    asm("v_med3_f32 %0, %1, %2, %3" : "=v"(r) : "v"(a), "v"(b), "v"(c));
    return r;
#endif
}

__global__ void init_pool_kernel(unsigned* __restrict__ pool) {
    int i = blockIdx.x * blockDim.x + threadIdx.x;
    if (i < BATCH * CH) pool[i] = 0u;   // 0 is below every encoded finite float
}

// Block: 256 threads = 4 waves. Lane l owns query (qg*64 + l); wave w scans
// candidate chunk [w*1024, w*1024+1024) from LDS-staged SoA planes.
__launch_bounds__(256, 2)
__global__ void knn_feat_kernel(const float* __restrict__ x,
                                unsigned* __restrict__ pool) {
    extern __shared__ float smem[];
    float* __restrict__ psx = smem;                 // [NPTS] 16 KB
    float* __restrict__ psy = smem + NPTS;          // [NPTS] 16 KB
    float* __restrict__ psz = smem + 2 * NPTS;      // [NPTS] 16 KB
    float* __restrict__ buf = smem + 3 * NPTS;      // [NW*KNN*64] 32 KB

    const int b   = blockIdx.x >> 6;                // 64 query-groups per batch
    const int qg  = blockIdx.x & 63;
    const int tid = threadIdx.x;
    const int w   = tid >> 6;                       // wave id = chunk id
    const int l   = tid & 63;                       // lane = query slot
    const int q   = qg * 64 + l;
    const float* __restrict__ xb = x + (size_t)b * NPTS * 3;

    // Stage the whole batch as 3 SoA planes.
    for (int pt = tid; pt < NPTS; pt += 256) {
        psx[pt] = xb[pt * 3 + 0];
        psy[pt] = xb[pt * 3 + 1];
        psz[pt] = xb[pt * 3 + 2];
    }
    __syncthreads();

    const float qx = psx[q], qy = psy[q], qz = psz[q];
    const float qw = qx * qx + qy * qy + qz * qz;

    // ---- Pass 1: top-32 distance VALUES of my chunk (sorted asc). ----
    // med3 insert: branch-free, 32 inst, depth-1 dependency per candidate.
    float arr[KNN];
#pragma unroll
    for (int j = 0; j < KNN; ++j) arr[j] = INF_F;

    {
        const int base = w * CHUNK;
        for (int m = 0; m < CHUNK; ++m) {
            float px = psx[base + m], py = psy[base + m], pz = psz[base + m];
            float pw  = px * px + py * py + pz * pz;   // bit-identical both passes
            float dot = qx * px + qy * py + qz * pz;
            float d   = qw + pw - 2.0f * dot;
#pragma unroll
            for (int j = KNN - 1; j >= 1; --j)
                arr[j] = med3f(arr[j - 1], arr[j], d);  // reads OLD arr[j-1]
            arr[0] = fminf(arr[0], d);
        }
    }

#pragma unroll
    for (int j = 0; j < KNN; ++j) buf[(w * KNN + j) * 64 + l] = arr[j];
    __syncthreads();

    // ---- Merge the 4 sorted lists for query l (done redundantly per wave):
    // thr = 32nd smallest of the union == global 32nd smallest distance.
    float thr;
    {
        float v0 = buf[(0 * KNN) * 64 + l];
        float v1 = buf[(1 * KNN) * 64 + l];
        float v2 = buf[(2 * KNN) * 64 + l];
        float v3 = buf[(3 * KNN) * 64 + l];
        int h0 = 1, h1 = 1, h2 = 1, h3 = 1;
        float mv = 0.f;
#pragma unroll 1
        for (int it = 0; it < KNN; ++it) {
            mv = fminf(fminf(v0, v1), fminf(v2, v3));
            if (it == KNN - 1) break;
            if (v0 == mv)      { v0 = (h0 < KNN) ? buf[(0 * KNN + h0) * 64 + l] : INF_F; ++h0; }
            else if (v1 == mv) { v1 = (h1 < KNN) ? buf[(1 * KNN + h1) * 64 + l] : INF_F; ++h1; }
            else if (v2 == mv) { v2 = (h2 < KNN) ? buf[(2 * KNN + h2) * 64 + l] : INF_F; ++h2; }
            else               { v3 = (h3 < KNN) ? buf[(3 * KNN + h3) * 64 + l] : INF_F; ++h3; }
        }
        thr = mv;
    }

    // Counts per chunk: everything < thr is provably inside its chunk's top-32.
    int lt0 = 0, lt1 = 0, lt2 = 0, lt3 = 0;
    int eq0 = 0, eq1 = 0, eq2 = 0, eq3 = 0;
#pragma unroll
    for (int j = 0; j < KNN; ++j) {
        float a0 = buf[(0 * KNN + j) * 64 + l]; lt0 += a0 < thr; eq0 += a0 == thr;
        float a1 = buf[(1 * KNN + j) * 64 + l]; lt1 += a1 < thr; eq1 += a1 == thr;
        float a2 = buf[(2 * KNN + j) * 64 + l]; lt2 += a2 < thr; eq2 += a2 == thr;
        float a3 = buf[(3 * KNN + j) * 64 + l]; lt3 += a3 < thr; eq3 += a3 == thr;
    }
    const int need = KNN - (lt0 + lt1 + lt2 + lt3);   // ties to take globally
    int before, quota;
    if (w == 0)      before = 0;
    else if (w == 1) before = eq0;
    else if (w == 2) before = eq0 + eq1;
    else             before = eq0 + eq1 + eq2;
    quota = need - before;
    if (quota < 0) quota = 0;                          // ties taken in index order

    __syncthreads();   // all list reads done; buf will be reused for stats

    // ---- Pass 2: accumulate neighbor statistics over my chunk. ----
    float s0 = 0.f, s1 = 0.f, s2 = 0.f;
    float ss0 = 0.f, ss1 = 0.f, ss2 = 0.f;
    float mx0 = -INF_F, mx1 = -INF_F, mx2 = -INF_F;
    float mn0 =  INF_F, mn1 =  INF_F, mn2 =  INF_F;
    int taken_eq = 0;
    {
        const int base = w * CHUNK;
        for (int m = 0; m < CHUNK; ++m) {
            float px = psx[base + m], py = psy[base + m], pz = psz[base + m];
            float pw  = px * px + py * py + pz * pz;
            float dot = qx * px + qy * py + qz * pz;
            float d   = qw + pw - 2.0f * dot;          // bit-identical to pass 1
            bool take = d < thr;
            if (!take && d == thr && taken_eq < quota) { take = true; ++taken_eq; }
            if (take) {
                float r0 = px - qx, r1 = py - qy, r2 = pz - qz;
                s0 += r0;  s1 += r1;  s2 += r2;
                ss0 += r0 * r0;  ss1 += r1 * r1;  ss2 += r2 * r2;
                mx0 = fmaxf(mx0, r0); mx1 = fmaxf(mx1, r1); mx2 = fmaxf(mx2, r2);
                mn0 = fminf(mn0, r0); mn1 = fminf(mn1, r1); mn2 = fminf(mn2, r2);
            }
        }
    }

    // Stash partial stats [w][c][l] (12 channels), reusing buf.
    buf[(w * 12 +  0) * 64 + l] = s0;   buf[(w * 12 +  1) * 64 + l] = s1;
    buf[(w * 12 +  2) * 64 + l] = s2;   buf[(w * 12 +  3) * 64 + l] = ss0;
    buf[(w * 12 +  4) * 64 + l] = ss1;  buf[(w * 12 +  5) * 64 + l] = ss2;
    buf[(w * 12 +  6) * 64 + l] = mx0;  buf[(w * 12 +  7) * 64 + l] = mx1;
    buf[(w * 12 +  8) * 64 + l] = mx2;  buf[(w * 12 +  9) * 64 + l] = mn0;
    buf[(w * 12 + 10) * 64 + l] = mn1;  buf[(w * 12 + 11) * 64 + l] = mn2;
    __syncthreads();

    if (w != 0) return;   // no barriers past this point

    // ---- Combine 4 partials, build 30 channels, wave-max, one atomic. ----
#define RD(ww, c) buf[((ww) * 12 + (c)) * 64 + l]
    s0  = RD(0,0) + RD(1,0) + RD(2,0) + RD(3,0);
    s1  = RD(0,1) + RD(1,1) + RD(2,1) + RD(3,1);
    s2  = RD(0,2) + RD(1,2) + RD(2,2) + RD(3,2);
    ss0 = RD(0,3) + RD(1,3) + RD(2,3) + RD(3,3);
    ss1 = RD(0,4) + RD(1,4) + RD(2,4) + RD(3,4);
    ss2 = RD(0,5) + RD(1,5) + RD(2,5) + RD(3,5);
    mx0 = fmaxf(fmaxf(RD(0,6), RD(1,6)), fmaxf(RD(2,6), RD(3,6)));
    mx1 = fmaxf(fmaxf(RD(0,7), RD(1,7)), fmaxf(RD(2,7), RD(3,7)));
    mx2 = fmaxf(fmaxf(RD(0,8), RD(1,8)), fmaxf(RD(2,8), RD(3,8)));
    mn0 = fminf(fminf(RD(0,9), RD(1,9)), fminf(RD(2,9), RD(3,9)));
    mn1 = fminf(fminf(RD(0,10), RD(1,10)), fminf(RD(2,10), RD(3,10)));
    mn2 = fminf(fminf(RD(0,11), RD(1,11)), fminf(RD(2,11), RD(3,11)));
#undef RD

    const float invk = 1.0f / (float)KNN;
    float mu0 = s0 * invk, mu1 = s1 * invk, mu2 = s2 * invk;
    float ex0 = ss0 * invk, ex1 = ss1 * invk, ex2 = ss2 * invk;
    float st0 = sqrtf(fmaxf(ex0 - mu0 * mu0, 0.f));
    float st1 = sqrtf(fmaxf(ex1 - mu1 * mu1, 0.f));
    float st2 = sqrtf(fmaxf(ex2 - mu2 * mu2, 0.f));
    float nrm = sqrtf(mu0 * mu0 + mu1 * mu1 + mu2 * mu2) + 1e-8f;
    float u0 = mu0 / nrm, u1 = mu1 / nrm, u2 = mu2 / nrm;
    float cr0 = qy * u2 - qz * u1;
    float cr1 = qz * u0 - qx * u2;
    float cr2 = qx * u1 - qy * u0;
    float mq0 = fmaxf(mx0 * mx0, mn0 * mn0);
    float mq1 = fmaxf(mx1 * mx1, mn1 * mn1);
    float mq2 = fmaxf(mx2 * mx2, mn2 * mn2);

    float f[CH] = { qx, qy, qz,
                    mu0, mu1, mu2,
                    mx0, mx1, mx2,
                    mn0, mn1, mn2,
                    st0, st1, st2,
                    qx - mu0, qy - mu1, qz - mu2,
                    u0, u1, u2,
                    cr0, cr1, cr2,
                    mq0, mq1, mq2,
                    ex0, ex1, ex2 };

#pragma unroll
    for (int c = 0; c < CH; ++c) {
        float v = f[c];
#pragma unroll
        for (int off = 32; off >= 1; off >>= 1)
            v = fmaxf(v, __shfl_xor(v, off, 64));
        if (l == 0)
            atomicMax(pool + b * CH + c, enc_f32(v));
    }
}

__global__ void final_mm_kernel(const unsigned* __restrict__ pool,
                                const float* __restrict__ W,
                                const float* __restrict__ bias,
                                float* __restrict__ out) {
    int t = blockIdx.x * blockDim.x + threadIdx.x;
    if (t >= BATCH * 32) return;
    int bb = t >> 5, e = t & 31;
    float acc = bias[e];
#pragma unroll
    for (int c = 0; c < CH; ++c)
        acc += dec_f32(pool[bb * CH + c]) * W[e * CH + c];
    out[bb * 32 + e] = acc;
}

extern "C" void kernel_launch(void* const* d_in, const int* in_sizes, int n_in,
                              void* d_out, int out_size, void* d_ws, size_t ws_size,
                              hipStream_t stream) {
    const float* x    = (const float*)d_in[0];   // [16, 4096, 3] f32
    const float* W    = (const float*)d_in[1];   // [32, 30] f32
    const float* bias = (const float*)d_in[2];   // [32] f32
    float*       out  = (float*)d_out;           // [16, 32] f32
    unsigned*    pool = (unsigned*)d_ws;         // [16, 30] encoded f32

    const size_t lds_bytes = (size_t)(3 * NPTS + NW * KNN * 64) * sizeof(float); // 80 KB

    hipLaunchKernelGGL(init_pool_kernel, dim3(1), dim3(512), 0, stream, pool);
    hipLaunchKernelGGL(knn_feat_kernel, dim3(BATCH * (NPTS / 64)), dim3(256),
                       lds_bytes, stream, x, pool);
    hipLaunchKernelGGL(final_mm_kernel, dim3(1), dim3(512), 0, stream, pool, W, bias, out);
}